// Round 5
// baseline (25.708 us; speedup 1.0000x reference)
//
#include <hip/hip_runtime.h>

typedef short bf16x8 __attribute__((ext_vector_type(8)));
typedef float f32x4 __attribute__((ext_vector_type(4)));
typedef ushort u16x8 __attribute__((ext_vector_type(8)));

#define MFMA16(A, B, C) __builtin_amdgcn_mfma_f32_16x16x32_bf16((A), (B), (C), 0, 0, 0)

static __device__ __forceinline__ ushort f2bf(float f) {
    unsigned u = __builtin_bit_cast(unsigned, f);
    unsigned r = (u + 0x7FFFu + ((u >> 16) & 1u)) >> 16;
    return (ushort)r;
}
static __device__ __forceinline__ unsigned pk2(float a, float b) {
    return (unsigned)f2bf(a) | ((unsigned)f2bf(b) << 16);
}
static __device__ __forceinline__ bf16x8 ldg8(const ushort* p) {
    uint4 u = *(const uint4*)p;
    return __builtin_bit_cast(bf16x8, u);
}

// ---- workspace layout (bytes) ----
// kT : [2][24][32pad][512] bf16            @ 0        size 1572864
// v4 : [4][2][512][25][32pad] bf16         @ 1572864  size 6553600
// total 8126464   (Q is consumed directly from f32 by attn — no transpose copy)
#define OFF_KT 0
#define OFF_V4 1572864
#define WS_NEED 8126464

// Fused K/V prep (unchanged from R4):
//   blocks [0, 576)     : k -> kT bf16 [2][24][32pad][512] (pad cols unwritten:
//                         they only feed softmax-masked tap positions)
//   blocks [576, 2176)  : v -> v4 gather [4][2][512][25][32pad], full coverage
__global__ __launch_bounds__(256) void prep(const float* __restrict__ k,
                                            const float* __restrict__ v,
                                            ushort* __restrict__ kt,
                                            ushort* __restrict__ v4) {
    __shared__ float tile[32][33];
    int bid = blockIdx.x;

    if (bid < 576) {
        int b = bid / 288;
        int rem = bid % 288;
        int p0 = (rem / 16) * 32;
        int c0 = (rem % 16) * 32;
        int tx = threadIdx.x & 31, tw = threadIdx.x >> 5;
#pragma unroll
        for (int i = 0; i < 4; ++i) {
            int r = tw + i * 8;
            tile[r][tx] = k[(size_t)(b * 512 + c0 + r) * 576 + p0 + tx];
        }
        __syncthreads();
#pragma unroll
        for (int i = 0; i < 4; ++i) {
            int r = tw + i * 8;
            int pix = p0 + r;
            int kr = pix / 24, kc = pix % 24;
            kt[((size_t)(b * 24 + kr) * 32 + kc) * 512 + c0 + tx] = f2bf(tile[tx][r]);
        }
    } else {
        int tid = (bid - 576) * 256 + threadIdx.x;  // 409600 threads total
        int col0 = (tid & 3) * 8;
        int rowlin = tid >> 2;
        int kr = rowlin % 25;
        int c = (rowlin / 25) % 512;
        int b = (rowlin / (25 * 512)) & 1;
        int s = rowlin / (25 * 512 * 2);
        const float* src = v + (size_t)(b * 512 + c) * 576 + kr * 24;
        u16x8 w;
#pragma unroll
        for (int j = 0; j < 8; ++j) {
            int srcc = col0 + j + 2 * s;
            w[j] = (kr < 24 && srcc < 24) ? f2bf(src[srcc]) : (ushort)0;
        }
        *(u16x8*)&v4[(size_t)rowlin * 32 + col0] = w;
    }
}

// Two waves per (2x8 pixel tile, head), split along the 64-channel k-dim.
// 2304 blocks x 128 threads.
//   wave w computes QK^T partial over channels [h*64+32w, h*64+32w+32)  (9 MFMA)
//   wave 1 -> partials to LDS; wave 0 sums, softmax, P*(1/sum) -> LDS bf16
//   PV split by output-channel halves: wave w does md = 2w, 2w+1 (10 MFMA)
__global__ __launch_bounds__(128) void attn(const float* __restrict__ q,
                                            const ushort* __restrict__ kt,
                                            const ushort* __restrict__ v4,
                                            float* __restrict__ out) {
    __shared__ float Xch[36][64];                    // wave1 partial scores
    __shared__ __align__(16) unsigned Plds[16][84];  // [pixel][160 taps as bf16 pairs]

    int bid = blockIdx.x;
    int h = bid & 7;
    int t = bid >> 3;
    int tx = t % 6;
    int tyb = t / 6;  // 0..47
    int ty = tyb % 24;
    int b = tyb / 24;

    int l = threadIdx.x & 63;
    int w = threadIdx.x >> 6;
    int pix = l & 15, g = l >> 4;
    int px = pix & 7, py = pix >> 3;
    int y = ty * 2 + py, x = tx * 8 + px;

    int sr = min(max(ty - 4, 0), 15);            // shared row start (all 16 pixels)
    int sw0 = min(max(4 * tx - 4, 0), 15);       // col start of first pixel
    int swe = sw0 & ~1;                          // even base of col-union
    int sw = min(max((x >> 1) - 4, 0), 15);      // this pixel's col start
    int dx = sw - swe;                           // 0..4: valid tap cols = [dx, dx+8]
    int s2 = swe & 6, scopy = s2 >> 1, colbase = swe - s2;  // colbase in {0,8}

    // Q fragment for this wave's 32-channel block: channels h*64+32w+g*8+j
    const float* qsrc = q + (size_t)(b * 512 + h * 64 + w * 32 + g * 8) * 2304 + y * 48 + x;
    float t0[8];
#pragma unroll
    for (int j = 0; j < 8; ++j) t0[j] = qsrc[(size_t)j * 2304];
    bf16x8 q0;
#pragma unroll
    for (int j = 0; j < 8; ++j) q0[j] = (short)f2bf(t0[j]);

    // QK^T partial (swapped): S^T[tap][pixel], 9 mtiles of 16 taps, K=32
    f32x4 sc[9];
#pragma unroll
    for (int m = 0; m < 9; ++m) {
        int koff = (((b * 24 + sr + m) << 5) + swe + pix) * 512 + h * 64 + w * 32 + g * 8;
        f32x4 a = {0.f, 0.f, 0.f, 0.f};
        a = MFMA16(ldg8(kt + koff), q0, a);
        sc[m] = a;
    }

    if (w == 1) {
#pragma unroll
        for (int m = 0; m < 9; ++m) {
#pragma unroll
            for (int r = 0; r < 4; ++r) Xch[m * 4 + r][l] = sc[m][r];
        }
    }
    __syncthreads();

    if (w == 0) {
        // sum partials; masked softmax; fold 1/sum into P; write P to LDS
#pragma unroll
        for (int m = 0; m < 9; ++m) {
#pragma unroll
            for (int r = 0; r < 4; ++r) sc[m][r] += Xch[m * 4 + r][l];
        }
        const float C2 = 0.18033688011112042f;  // 0.125 * log2(e)
        float mx = -3.0e38f;
#pragma unroll
        for (int r = 0; r < 4; ++r) {
            if ((unsigned)(g * 4 + r - dx) <= 8u) {
#pragma unroll
                for (int m = 0; m < 9; ++m) mx = fmaxf(mx, sc[m][r]);
            }
        }
        mx = fmaxf(mx, __shfl_xor(mx, 16));
        mx = fmaxf(mx, __shfl_xor(mx, 32));
        float sum = 0.f;
#pragma unroll
        for (int m = 0; m < 9; ++m) {
#pragma unroll
            for (int r = 0; r < 4; ++r) {
                bool valid = (unsigned)(g * 4 + r - dx) <= 8u;
                float p = valid ? exp2f((sc[m][r] - mx) * C2) : 0.f;
                sc[m][r] = p;
                sum += p;
            }
        }
        sum += __shfl_xor(sum, 16);
        sum += __shfl_xor(sum, 32);
        float invd = 1.0f / sum;
#pragma unroll
        for (int m = 0; m < 9; ++m) {
            uint2 pw;
            pw.x = pk2(sc[m][0] * invd, sc[m][1] * invd);
            pw.y = pk2(sc[m][2] * invd, sc[m][3] * invd);
            *(uint2*)&Plds[pix][m * 8 + g * 2] = pw;
        }
        *(uint2*)&Plds[pix][72 + g * 2] = make_uint2(0u, 0u);  // taps 144..159 = 0
    }
    __syncthreads();

    // PV (swapped): out^T[d][pixel] = V^T (A) x P^T (B), K = 160 taps
    // wave w handles md = 2w, 2w+1
    f32x4 o[2] = {{0.f, 0.f, 0.f, 0.f}, {0.f, 0.f, 0.f, 0.f}};
#pragma unroll
    for (int ks = 0; ks < 5; ++ks) {
        uint4 pw = *(const uint4*)&Plds[pix][ks * 16 + g * 4];
        bf16x8 pf = __builtin_bit_cast(bf16x8, pw);
        int tap0 = ks * 32 + g * 8;
        int tr = tap0 >> 4, tc0 = tap0 & 15;
#pragma unroll
        for (int i = 0; i < 2; ++i) {
            int c = h * 64 + (2 * w + i) * 16 + pix;
            const ushort* vp = v4 + ((size_t)((scopy * 2 + b) * 512 + c) * 25 + sr + tr) * 32 + colbase + tc0;
            o[i] = MFMA16(ldg8(vp), pf, o[i]);
        }
    }

#pragma unroll
    for (int i = 0; i < 2; ++i) {
#pragma unroll
        for (int r = 0; r < 4; ++r) {
            int d = (2 * w + i) * 16 + g * 4 + r;
            out[((size_t)(b * 512 + h * 64 + d) * 48 + y) * 48 + x] = o[i][r];
        }
    }
}

extern "C" void kernel_launch(void* const* d_in, const int* in_sizes, int n_in,
                              void* d_out, int out_size, void* d_ws, size_t ws_size,
                              hipStream_t stream) {
    const float* q = (const float*)d_in[0];
    const float* k = (const float*)d_in[1];
    const float* v = (const float*)d_in[2];
    float* out = (float*)d_out;
    char* ws = (char*)d_ws;
    if (ws_size < (size_t)WS_NEED) return;

    ushort* kt = (ushort*)(ws + OFF_KT);
    ushort* v4 = (ushort*)(ws + OFF_V4);

    prep<<<2176, 256, 0, stream>>>(k, v, kt, v4);
    attn<<<2304, 128, 0, stream>>>(q, kt, v4, out);
}